// Round 1
// baseline (294.712 us; speedup 1.0000x reference)
//
#include <hip/hip_runtime.h>
#include <hip/hip_bf16.h>

#define GLOBAL_AS __attribute__((address_space(1)))
#define LDS_AS    __attribute__((address_space(3)))

typedef __bf16 bf16x8 __attribute__((ext_vector_type(8)));
typedef float  f32x4v __attribute__((ext_vector_type(4)));

__device__ __forceinline__ unsigned short f2bf(float f) {
    union { float f; unsigned int u; } a; a.f = f;
    unsigned int u = a.u;
    u += 0x7FFFu + ((u >> 16) & 1u);           // round-to-nearest-even
    return (unsigned short)(u >> 16);
}

// ---------------- K1: RMSNorm -> t_f32, t_bf16 ----------------
__global__ __launch_bounds__(256) void k_rmsnorm(const float* __restrict__ x,
        const float* __restrict__ sc, float* __restrict__ t32,
        unsigned short* __restrict__ t16)
{
    const int t = blockIdx.x, tid = threadIdx.x;
    const float4 v = ((const float4*)(x + (size_t)t * 1024))[tid];
    float ss = v.x*v.x + v.y*v.y + v.z*v.z + v.w*v.w;
    #pragma unroll
    for (int s = 32; s; s >>= 1) ss += __shfl_xor(ss, s, 64);
    __shared__ float red[4];
    if ((tid & 63) == 0) red[tid >> 6] = ss;
    __syncthreads();
    const float tot = red[0] + red[1] + red[2] + red[3];
    const float rs = rsqrtf(tot * (1.0f / 1024.0f) + 1e-5f);
    const float4 s4 = ((const float4*)sc)[tid];
    float4 o;
    o.x = v.x * rs * s4.x; o.y = v.y * rs * s4.y;
    o.z = v.z * rs * s4.z; o.w = v.w * rs * s4.w;
    ((float4*)(t32 + (size_t)t * 1024))[tid] = o;
    uint2 p;
    p.x = (unsigned)f2bf(o.x) | ((unsigned)f2bf(o.y) << 16);
    p.y = (unsigned)f2bf(o.z) | ((unsigned)f2bf(o.w) << 16);
    ((uint2*)(t16 + (size_t)t * 1024))[tid] = p;
}

// ---------------- K2: gate logits (fp32 exact) + top4 + softmax ----------------
__global__ __launch_bounds__(64) void k_gate(const float* __restrict__ t32,
        const float* __restrict__ gw, const float* __restrict__ gb,
        int* __restrict__ idx, float* __restrict__ ew)
{
    const int t = blockIdx.x, tid = threadIdx.x;   // 64 threads, one per expert
    __shared__ float4 tl[256];
    __shared__ float lg[64];
    const float4* xr = (const float4*)(t32 + (size_t)t * 1024);
    #pragma unroll
    for (int i = 0; i < 4; ++i) tl[i * 64 + tid] = xr[i * 64 + tid];
    __syncthreads();
    const float4* w4 = (const float4*)(gw + (size_t)tid * 1024);
    float acc = gb[tid];
    for (int k = 0; k < 256; ++k) {
        const float4 a = tl[k], b = w4[k];
        acc += a.x*b.x; acc += a.y*b.y; acc += a.z*b.z; acc += a.w*b.w;
    }
    lg[tid] = acc;
    __syncthreads();
    if (tid == 0) {
        unsigned long long taken = 0ull;
        float vals[4]; int ids[4];
        for (int k = 0; k < 4; ++k) {
            float bv = -3.0e38f; int bi = 0;
            for (int e = 0; e < 64; ++e) {
                if ((taken >> e) & 1ull) continue;
                if (lg[e] > bv) { bv = lg[e]; bi = e; }
            }
            taken |= 1ull << bi; vals[k] = bv; ids[k] = bi;
        }
        float ex[4], s = 0.0f;
        for (int k = 0; k < 4; ++k) { ex[k] = expf(vals[k] - vals[0]); s += ex[k]; }
        const float inv = 1.0f / s;
        for (int k = 0; k < 4; ++k) { idx[t*4+k] = ids[k]; ew[t*4+k] = ex[k] * inv; }
    }
}

// ---------------- K3: bucket (token,expert) pairs by expert ----------------
__global__ __launch_bounds__(256) void k_bucket(const int* __restrict__ idx,
        const float* __restrict__ ewv, int* __restrict__ eoff,
        int* __restrict__ slot_token, float* __restrict__ slot_ew,
        int* __restrict__ token_slots)
{
    __shared__ int cnt[64], cur[64];
    const int tid = threadIdx.x;
    if (tid < 64) cnt[tid] = 0;
    __syncthreads();
    for (int p = tid; p < 4096; p += 256) atomicAdd(&cnt[idx[p]], 1);
    __syncthreads();
    if (tid == 0) {
        int s = 0;
        for (int e = 0; e < 64; ++e) { eoff[e] = s; cur[e] = s; s += cnt[e]; }
        eoff[64] = s;
    }
    __syncthreads();
    for (int p = tid; p < 4096; p += 256) {
        const int e = idx[p];
        const int s = atomicAdd(&cur[e], 1);
        slot_token[s] = p >> 2;
        slot_ew[s] = ewv[p];
        token_slots[p] = s;
    }
}

// ---------------- K4/K5: grouped GEMM, 128x128 tile, BK=64, bf16 MFMA ----------------
// MODE 0: h = W1[e] @ t  (+bias, SwiGLU fused) -> act bf16   (N per expert = 2048)
// MODE 1: o = W2[e] @ act (+bias, *gate weight) -> o_buf f32 (N per expert = 1024)
template<int MODE>
__global__ __launch_bounds__(256, 2) void k_gemm(
        const float* __restrict__ W, const float* __restrict__ Bias,
        const unsigned short* __restrict__ A,
        const int* __restrict__ eoff, const int* __restrict__ slot_token,
        const float* __restrict__ slot_ew,
        unsigned short* __restrict__ act_out, float* __restrict__ o_buf)
{
    constexpr int NPE = (MODE == 0) ? 2048 : 1024;
    const int e  = blockIdx.y;
    const int nt = blockIdx.x;
    const int off = eoff[e];
    const int count = eoff[e + 1] - off;
    if (count == 0) return;
    const int tid = threadIdx.x;
    const int wv = tid >> 6, l = tid & 63;
    const int wm = wv >> 1, wn = wv & 1;

    __shared__ unsigned char lds[2][32768];   // per buf: A[128][64]bf16 (16KB) then B (16KB)

    const float* Wb = W + (size_t)e * NPE * 1024 + (size_t)nt * 128 * 1024;

    for (int mt = 0; mt * 128 < count; ++mt) {
        // per-lane A source pointers (pre-swizzled global so linear LDS dest + swizzled read agree)
        const unsigned char* asrc[4];
        #pragma unroll
        for (int i = 0; i < 4; ++i) {
            const int chunk = wv * 4 + i;
            const int row = chunk * 8 + (l >> 3);       // row & 7 == l >> 3
            const int colbyte = ((l & 7) ^ (l >> 3)) << 4;
            int arow;
            if (MODE == 0) {
                int slot = off + mt * 128 + row;
                const int smax = off + count - 1;
                if (slot > smax) slot = smax;           // clamp pad rows (results discarded)
                arow = slot_token[slot];
            } else {
                arow = off + mt * 128 + row;            // act has 4224 rows of slack
            }
            asrc[i] = (const unsigned char*)A + (size_t)arow * 2048 + colbyte;
        }

        f32x4v acc[4][4];
        #pragma unroll
        for (int m = 0; m < 4; ++m)
            #pragma unroll
            for (int n = 0; n < 4; ++n)
                acc[m][n] = f32x4v{0.f, 0.f, 0.f, 0.f};

        float4 bv[8];

        // prologue: stage kt=0 into buf 0
        #pragma unroll
        for (int i = 0; i < 4; ++i)
            __builtin_amdgcn_global_load_lds((const GLOBAL_AS void*)asrc[i],
                (LDS_AS void*)&lds[0][(wv * 4 + i) * 1024], 16, 0, 0);
        #pragma unroll
        for (int it = 0; it < 8; ++it) {
            const int fid = it * 256 + tid;
            bv[it] = *(const float4*)(Wb + (size_t)(fid >> 4) * 1024 + (fid & 15) * 4);
        }
        #pragma unroll
        for (int it = 0; it < 8; ++it) {
            const int fid = it * 256 + tid;
            const int row = fid >> 4, c4 = fid & 15;
            uint2 p;
            p.x = (unsigned)f2bf(bv[it].x) | ((unsigned)f2bf(bv[it].y) << 16);
            p.y = (unsigned)f2bf(bv[it].z) | ((unsigned)f2bf(bv[it].w) << 16);
            *(uint2*)(&lds[0][16384 + row * 128 + ((c4 * 8) ^ ((row & 7) << 4))]) = p;
        }
        __syncthreads();

        int buf = 0;
        for (int kt = 0; kt < 16; ++kt) {
            const bool pf = (kt < 15);
            if (pf) {
                #pragma unroll
                for (int i = 0; i < 4; ++i)
                    __builtin_amdgcn_global_load_lds(
                        (const GLOBAL_AS void*)(asrc[i] + (kt + 1) * 128),
                        (LDS_AS void*)&lds[buf ^ 1][(wv * 4 + i) * 1024], 16, 0, 0);
                #pragma unroll
                for (int it = 0; it < 8; ++it) {
                    const int fid = it * 256 + tid;
                    bv[it] = *(const float4*)(Wb + (size_t)(fid >> 4) * 1024
                                              + (kt + 1) * 64 + (fid & 15) * 4);
                }
            }
            // compute on buf
            #pragma unroll
            for (int kk = 0; kk < 2; ++kk) {
                bf16x8 af[4], bfr[4];
                #pragma unroll
                for (int m = 0; m < 4; ++m) {
                    const int row = wm * 64 + m * 16 + (l & 15);
                    af[m] = *(const bf16x8*)(&lds[buf][row * 128 +
                              ((kk * 64 + ((l >> 4) * 16)) ^ ((row & 7) << 4))]);
                }
                #pragma unroll
                for (int n = 0; n < 4; ++n) {
                    const int row = wn * 64 + n * 16 + (l & 15);
                    bfr[n] = *(const bf16x8*)(&lds[buf][16384 + row * 128 +
                              ((kk * 64 + ((l >> 4) * 16)) ^ ((row & 7) << 4))]);
                }
                #pragma unroll
                for (int m = 0; m < 4; ++m)
                    #pragma unroll
                    for (int n = 0; n < 4; ++n)
                        acc[m][n] = __builtin_amdgcn_mfma_f32_16x16x32_bf16(
                                        af[m], bfr[n], acc[m][n], 0, 0, 0);
            }
            if (pf) {
                #pragma unroll
                for (int it = 0; it < 8; ++it) {
                    const int fid = it * 256 + tid;
                    const int row = fid >> 4, c4 = fid & 15;
                    uint2 p;
                    p.x = (unsigned)f2bf(bv[it].x) | ((unsigned)f2bf(bv[it].y) << 16);
                    p.y = (unsigned)f2bf(bv[it].z) | ((unsigned)f2bf(bv[it].w) << 16);
                    *(uint2*)(&lds[buf ^ 1][16384 + row * 128 +
                              ((c4 * 8) ^ ((row & 7) << 4))]) = p;
                }
            }
            __syncthreads();
            buf ^= 1;
        }

        // epilogue
        #pragma unroll
        for (int m = 0; m < 4; ++m) {
            #pragma unroll
            for (int n = 0; n < 4; ++n) {
                #pragma unroll
                for (int j = 0; j < 4; ++j) {
                    const int row  = wm * 64 + m * 16 + (l >> 4) * 4 + j;
                    const int coll = wn * 64 + n * 16 + (l & 15);
                    const int gn = nt * 128 + coll;
                    const int gm = mt * 128 + row;
                    if (MODE == 0) {
                        float v = acc[m][n][j] + Bias[(size_t)e * NPE + gn];
                        const float partner = __shfl_xor(v, 1, 64);  // pair (2c,2c+1)
                        if (!(l & 1) && gm < count) {
                            const float g  = fminf(v, 7.0f);
                            const float lv = fminf(fmaxf(partner, -7.0f), 7.0f);
                            const float r  = g / (1.0f + expf(-1.702f * g)) * (lv + 1.0f);
                            act_out[(size_t)(off + gm) * 1024 + (gn >> 1)] = f2bf(r);
                        }
                    } else {
                        if (gm < count) {
                            const int slot = off + gm;
                            const float v = acc[m][n][j] + Bias[(size_t)e * NPE + gn];
                            o_buf[(size_t)slot * 1024 + gn] = v * slot_ew[slot];
                        }
                    }
                }
            }
        }
    }
}

// ---------------- K6: out = x + sum_k o_buf[slot(t,k)] ----------------
__global__ __launch_bounds__(256) void k_combine(const float* __restrict__ x,
        const float* __restrict__ o_buf, const int* __restrict__ tslot,
        float* __restrict__ out)
{
    const int t = blockIdx.x, tid = threadIdx.x;
    float4 r = ((const float4*)(x + (size_t)t * 1024))[tid];
    #pragma unroll
    for (int k = 0; k < 4; ++k) {
        const int s = tslot[t * 4 + k];
        const float4 o = ((const float4*)(o_buf + (size_t)s * 1024))[tid];
        r.x += o.x; r.y += o.y; r.z += o.z; r.w += o.w;
    }
    ((float4*)(out + (size_t)t * 1024))[tid] = r;
}

extern "C" void kernel_launch(void* const* d_in, const int* in_sizes, int n_in,
                              void* d_out, int out_size, void* d_ws, size_t ws_size,
                              hipStream_t stream)
{
    const float* x   = (const float*)d_in[0];
    const float* nsc = (const float*)d_in[1];
    const float* gw  = (const float*)d_in[2];
    const float* gb  = (const float*)d_in[3];
    const float* w1  = (const float*)d_in[4];
    const float* b1  = (const float*)d_in[5];
    const float* w2  = (const float*)d_in[6];
    const float* b2  = (const float*)d_in[7];
    float* out = (float*)d_out;
    (void)in_sizes; (void)n_in; (void)out_size; (void)ws_size;

    char* ws = (char*)d_ws;
    float*          t32   = (float*)(ws);                                  // 4 MiB
    unsigned short* t16   = (unsigned short*)(ws + (4u  << 20));           // 2 MiB
    unsigned short* act   = (unsigned short*)(ws + (6u  << 20));           // 4224*1024*2 B
    float*          obuf  = (float*)(ws + (16u << 20));                    // 16 MiB
    int*            idx   = (int*)  (ws + (32u << 20));
    float*          ew    = (float*)(ws + (32u << 20) + 1 * 65536);
    int*            stok  = (int*)  (ws + (32u << 20) + 2 * 65536);
    float*          sew   = (float*)(ws + (32u << 20) + 3 * 65536);
    int*            tslot = (int*)  (ws + (32u << 20) + 4 * 65536);
    int*            eoff  = (int*)  (ws + (32u << 20) + 5 * 65536);

    k_rmsnorm<<<1024, 256, 0, stream>>>(x, nsc, t32, t16);
    k_gate   <<<1024,  64, 0, stream>>>(t32, gw, gb, idx, ew);
    k_bucket <<<   1, 256, 0, stream>>>(idx, ew, eoff, stok, sew, tslot);
    k_gemm<0><<<dim3(16, 64), 256, 0, stream>>>(w1, b1, t16, eoff, stok, sew, act, nullptr);
    k_gemm<1><<<dim3( 8, 64), 256, 0, stream>>>(w2, b2, act, eoff, stok, sew, nullptr, obuf);
    k_combine<<<1024, 256, 0, stream>>>(x, obuf, tslot, out);
}

// Round 2
// 287.073 us; speedup vs baseline: 1.0266x; 1.0266x over previous
//
#include <hip/hip_runtime.h>
#include <hip/hip_bf16.h>

#define GLOBAL_AS __attribute__((address_space(1)))
#define LDS_AS    __attribute__((address_space(3)))

typedef __bf16 bf16x8 __attribute__((ext_vector_type(8)));
typedef __bf16 bf16x4 __attribute__((ext_vector_type(4)));
typedef float  f32x4v __attribute__((ext_vector_type(4)));

// ---------------- K1: RMSNorm -> t_f32, t_bf16 ----------------
__global__ __launch_bounds__(256) void k_rmsnorm(const float* __restrict__ x,
        const float* __restrict__ sc, float* __restrict__ t32,
        __bf16* __restrict__ t16)
{
    const int t = blockIdx.x, tid = threadIdx.x;
    const float4 v = ((const float4*)(x + (size_t)t * 1024))[tid];
    float ss = v.x*v.x + v.y*v.y + v.z*v.z + v.w*v.w;
    #pragma unroll
    for (int s = 32; s; s >>= 1) ss += __shfl_xor(ss, s, 64);
    __shared__ float red[4];
    if ((tid & 63) == 0) red[tid >> 6] = ss;
    __syncthreads();
    const float tot = red[0] + red[1] + red[2] + red[3];
    const float rs = rsqrtf(tot * (1.0f / 1024.0f) + 1e-5f);
    const float4 s4 = ((const float4*)sc)[tid];
    float4 o;
    o.x = v.x * rs * s4.x; o.y = v.y * rs * s4.y;
    o.z = v.z * rs * s4.z; o.w = v.w * rs * s4.w;
    ((float4*)(t32 + (size_t)t * 1024))[tid] = o;
    bf16x4 p;
    p[0] = (__bf16)o.x; p[1] = (__bf16)o.y; p[2] = (__bf16)o.z; p[3] = (__bf16)o.w;
    ((bf16x4*)(t16 + (size_t)t * 1024))[tid] = p;
}

// ---------------- K2: gate logits (fp32) + top4 + softmax ----------------
__global__ __launch_bounds__(256) void k_gate(const float* __restrict__ t32,
        const float* __restrict__ gw, const float* __restrict__ gb,
        int* __restrict__ idx, float* __restrict__ ew)
{
    const int t = blockIdx.x, tid = threadIdx.x;
    __shared__ float4 tl[256];
    __shared__ float part[4][64];
    tl[tid] = ((const float4*)(t32 + (size_t)t * 1024))[tid];
    __syncthreads();
    const int q = tid >> 6, e = tid & 63;
    const float4* w4 = (const float4*)(gw + (size_t)e * 1024 + q * 256);
    const float4* a4 = &tl[q * 64];
    float acc = 0.0f;
    #pragma unroll 8
    for (int i = 0; i < 64; ++i) {
        const float4 a = a4[i], b = w4[i];
        acc += a.x*b.x + a.y*b.y + a.z*b.z + a.w*b.w;
    }
    part[q][e] = acc;
    __syncthreads();
    if (tid < 64) {
        float cur = part[0][tid] + part[1][tid] + part[2][tid] + part[3][tid] + gb[tid];
        float vals[4]; int ids[4];
        #pragma unroll
        for (int k = 0; k < 4; ++k) {
            float m = cur;
            #pragma unroll
            for (int s = 32; s; s >>= 1) m = fmaxf(m, __shfl_xor(m, s, 64));
            const unsigned long long b = __ballot(cur == m);
            const int bi = __ffsll(b) - 1;
            vals[k] = m; ids[k] = bi;
            if (tid == bi) cur = -3.0e38f;
        }
        float ex[4], s = 0.0f;
        #pragma unroll
        for (int k = 0; k < 4; ++k) { ex[k] = expf(vals[k] - vals[0]); s += ex[k]; }
        if (tid < 4) { idx[t * 4 + tid] = ids[tid]; ew[t * 4 + tid] = ex[tid] / s; }
    }
}

// ---------------- K3: bucket (token,expert) pairs by expert ----------------
__global__ __launch_bounds__(256) void k_bucket(const int* __restrict__ idx,
        const float* __restrict__ ewv, int* __restrict__ eoff,
        int* __restrict__ slot_token, float* __restrict__ slot_ew,
        int* __restrict__ token_slots)
{
    __shared__ int cnt[64], cur[64];
    const int tid = threadIdx.x;
    if (tid < 64) cnt[tid] = 0;
    __syncthreads();
    for (int p = tid; p < 4096; p += 256) atomicAdd(&cnt[idx[p]], 1);
    __syncthreads();
    if (tid == 0) {
        int s = 0;
        for (int e = 0; e < 64; ++e) { eoff[e] = s; cur[e] = s; s += cnt[e]; }
        eoff[64] = s;
    }
    __syncthreads();
    for (int p = tid; p < 4096; p += 256) {
        const int e = idx[p];
        const int s = atomicAdd(&cur[e], 1);
        slot_token[s] = p >> 2;
        slot_ew[s] = ewv[p];
        token_slots[p] = s;
    }
}

// ---------------- K4/K5: grouped GEMM, 128x128 tile, BK=64, bf16 MFMA ----------------
// Pipelined: A via global_load_lds (1-deep), B via 2-deep register prefetch,
// counted s_waitcnt vmcnt(8) + raw s_barrier (T3/T4) so B loads span barriers.
template<int MODE>
__global__ __launch_bounds__(256, 2) void k_gemm(
        const float* __restrict__ W, const float* __restrict__ Bias,
        const __bf16* __restrict__ A,
        const int* __restrict__ eoff, const int* __restrict__ slot_token,
        const float* __restrict__ slot_ew,
        __bf16* __restrict__ act_out, float* __restrict__ o_buf)
{
    constexpr int NPE = (MODE == 0) ? 2048 : 1024;
    const int e  = blockIdx.y;
    const int nt = blockIdx.x;
    const int off = eoff[e];
    const int count = eoff[e + 1] - off;
    if (count == 0) return;
    const int tid = threadIdx.x;
    const int wv = tid >> 6, l = tid & 63;
    const int wm = wv >> 1, wn = wv & 1;

    __shared__ __attribute__((aligned(16))) unsigned char lds[2][32768];

    const float* Wb = W + (size_t)e * NPE * 1024 + (size_t)nt * 128 * 1024;

#define DMA_A(sbuf, kt) do {                                                   \
    const int kk_ = (kt) > 15 ? 15 : (kt);                                     \
    _Pragma("unroll")                                                          \
    for (int i_ = 0; i_ < 4; ++i_)                                             \
        __builtin_amdgcn_global_load_lds(                                      \
            (const GLOBAL_AS void*)(asrc[i_] + kk_ * 128),                     \
            (LDS_AS void*)&lds[sbuf][(wv * 4 + i_) * 1024], 16, 0, 0);         \
    } while (0)

#define LOAD_B(dst, kt) do {                                                   \
    const int kk_ = (kt) > 15 ? 15 : (kt);                                     \
    _Pragma("unroll")                                                          \
    for (int it_ = 0; it_ < 8; ++it_) {                                        \
        const int fid_ = it_ * 256 + tid;                                      \
        dst[it_] = *(const float4*)(Wb + (size_t)(fid_ >> 4) * 1024            \
                                    + kk_ * 64 + (fid_ & 15) * 4);             \
    } } while (0)

#define WRITE_B(src, sbuf) do {                                                \
    _Pragma("unroll")                                                          \
    for (int it_ = 0; it_ < 8; ++it_) {                                        \
        const int fid_ = it_ * 256 + tid;                                      \
        const int row_ = fid_ >> 4, c4_ = fid_ & 15;                           \
        bf16x4 p_;                                                             \
        p_[0] = (__bf16)src[it_].x; p_[1] = (__bf16)src[it_].y;                \
        p_[2] = (__bf16)src[it_].z; p_[3] = (__bf16)src[it_].w;                \
        *(bf16x4*)(&lds[sbuf][16384 + row_ * 128 +                             \
                   ((c4_ * 8) ^ ((row_ & 7) << 4))]) = p_;                     \
    } } while (0)

#define COMPUTE(cbuf) do {                                                     \
    _Pragma("unroll")                                                          \
    for (int kk_ = 0; kk_ < 2; ++kk_) {                                        \
        bf16x8 af_[4], bf_[4];                                                 \
        _Pragma("unroll")                                                      \
        for (int m_ = 0; m_ < 4; ++m_) {                                       \
            const int row_ = wm * 64 + m_ * 16 + (l & 15);                     \
            af_[m_] = *(const bf16x8*)(&lds[cbuf][row_ * 128 +                 \
                      ((kk_ * 64 + ((l >> 4) * 16)) ^ ((row_ & 7) << 4))]);    \
        }                                                                      \
        _Pragma("unroll")                                                      \
        for (int n_ = 0; n_ < 4; ++n_) {                                       \
            const int row_ = wn * 64 + n_ * 16 + (l & 15);                     \
            bf_[n_] = *(const bf16x8*)(&lds[cbuf][16384 + row_ * 128 +         \
                      ((kk_ * 64 + ((l >> 4) * 16)) ^ ((row_ & 7) << 4))]);    \
        }                                                                      \
        _Pragma("unroll")                                                      \
        for (int m_ = 0; m_ < 4; ++m_)                                         \
            _Pragma("unroll")                                                  \
            for (int n_ = 0; n_ < 4; ++n_)                                     \
                acc[m_][n_] = __builtin_amdgcn_mfma_f32_16x16x32_bf16(         \
                                  af_[m_], bf_[n_], acc[m_][n_], 0, 0, 0);     \
    } } while (0)

    for (int mt = 0; mt * 128 < count; ++mt) {
        const unsigned char* asrc[4];
        #pragma unroll
        for (int i = 0; i < 4; ++i) {
            const int chunk = wv * 4 + i;
            const int row = chunk * 8 + (l >> 3);
            const int colbyte = ((l & 7) ^ (l >> 3)) << 4;
            int arow;
            if (MODE == 0) {
                int slot = off + mt * 128 + row;
                const int smax = off + count - 1;
                if (slot > smax) slot = smax;
                arow = slot_token[slot];
            } else {
                arow = off + mt * 128 + row;
            }
            asrc[i] = (const unsigned char*)A + (size_t)arow * 2048 + colbyte;
        }

        f32x4v acc[4][4];
        #pragma unroll
        for (int m = 0; m < 4; ++m)
            #pragma unroll
            for (int n = 0; n < 4; ++n)
                acc[m][n] = f32x4v{0.f, 0.f, 0.f, 0.f};

        float4 bvA[8], bvB[8];

        // ---- prologue: lds[0] <- {A(0), B(0)}, bvA <- B(1) in flight ----
        DMA_A(0, 0);
        __builtin_amdgcn_sched_barrier(0);
        LOAD_B(bvA, 0);
        WRITE_B(bvA, 0);                 // reg dep drains B(0) (and older A-dma)
        __builtin_amdgcn_sched_barrier(0);
        LOAD_B(bvA, 1);
        asm volatile("s_waitcnt lgkmcnt(0)" ::: "memory");
        __builtin_amdgcn_sched_barrier(0);
        __builtin_amdgcn_s_barrier();

        #pragma unroll 1
        for (int p = 0; p < 8; ++p) {
            const int kt0 = 2 * p, kt1 = 2 * p + 1;
            // even step: compute lds[0], stage lds[1]; bvA holds B(kt0+1)
            DMA_A(1, kt0 + 1);
            __builtin_amdgcn_sched_barrier(0);
            LOAD_B(bvB, kt0 + 2);
            __builtin_amdgcn_sched_barrier(0);
            COMPUTE(0);
            WRITE_B(bvA, 1);             // reg dep -> counted wait, keeps new loads in flight
            asm volatile("s_waitcnt vmcnt(8) lgkmcnt(0)" ::: "memory");
            __builtin_amdgcn_sched_barrier(0);
            __builtin_amdgcn_s_barrier();
            // odd step: compute lds[1], stage lds[0]; bvB holds B(kt1+1)
            DMA_A(0, kt1 + 1);
            __builtin_amdgcn_sched_barrier(0);
            LOAD_B(bvA, kt1 + 2);
            __builtin_amdgcn_sched_barrier(0);
            COMPUTE(1);
            WRITE_B(bvB, 0);
            asm volatile("s_waitcnt vmcnt(8) lgkmcnt(0)" ::: "memory");
            __builtin_amdgcn_sched_barrier(0);
            __builtin_amdgcn_s_barrier();
        }

        // ---- epilogue ----
        #pragma unroll
        for (int m = 0; m < 4; ++m) {
            #pragma unroll
            for (int n = 0; n < 4; ++n) {
                #pragma unroll
                for (int j = 0; j < 4; ++j) {
                    const int row  = wm * 64 + m * 16 + (l >> 4) * 4 + j;
                    const int coll = wn * 64 + n * 16 + (l & 15);
                    const int gn = nt * 128 + coll;
                    const int gm = mt * 128 + row;
                    if (MODE == 0) {
                        float v = acc[m][n][j] + Bias[(size_t)e * NPE + gn];
                        const float partner = __shfl_xor(v, 1, 64);
                        if (!(l & 1) && gm < count) {
                            const float g  = fminf(v, 7.0f);
                            const float lv = fminf(fmaxf(partner, -7.0f), 7.0f);
                            const float r  = g / (1.0f + expf(-1.702f * g)) * (lv + 1.0f);
                            act_out[(size_t)(off + gm) * 1024 + (gn >> 1)] = (__bf16)r;
                        }
                    } else {
                        if (gm < count) {
                            const int slot = off + gm;
                            const float v = acc[m][n][j] + Bias[(size_t)e * NPE + gn];
                            o_buf[(size_t)slot * 1024 + gn] = v * slot_ew[slot];
                        }
                    }
                }
            }
        }
    }
#undef DMA_A
#undef LOAD_B
#undef WRITE_B
#undef COMPUTE
}

// ---------------- K6: out = x + sum_k o_buf[slot(t,k)] ----------------
__global__ __launch_bounds__(256) void k_combine(const float* __restrict__ x,
        const float* __restrict__ o_buf, const int* __restrict__ tslot,
        float* __restrict__ out)
{
    const int t = blockIdx.x, tid = threadIdx.x;
    float4 r = ((const float4*)(x + (size_t)t * 1024))[tid];
    #pragma unroll
    for (int k = 0; k < 4; ++k) {
        const int s = tslot[t * 4 + k];
        const float4 o = ((const float4*)(o_buf + (size_t)s * 1024))[tid];
        r.x += o.x; r.y += o.y; r.z += o.z; r.w += o.w;
    }
    ((float4*)(out + (size_t)t * 1024))[tid] = r;
}

extern "C" void kernel_launch(void* const* d_in, const int* in_sizes, int n_in,
                              void* d_out, int out_size, void* d_ws, size_t ws_size,
                              hipStream_t stream)
{
    const float* x   = (const float*)d_in[0];
    const float* nsc = (const float*)d_in[1];
    const float* gw  = (const float*)d_in[2];
    const float* gb  = (const float*)d_in[3];
    const float* w1  = (const float*)d_in[4];
    const float* b1  = (const float*)d_in[5];
    const float* w2  = (const float*)d_in[6];
    const float* b2  = (const float*)d_in[7];
    float* out = (float*)d_out;
    (void)in_sizes; (void)n_in; (void)out_size; (void)ws_size;

    char* ws = (char*)d_ws;
    float*  t32   = (float*)(ws);                                  // 4 MiB
    __bf16* t16   = (__bf16*)(ws + (4u  << 20));                   // 2 MiB
    __bf16* act   = (__bf16*)(ws + (6u  << 20));                   // 4224*1024*2 B
    float*  obuf  = (float*)(ws + (16u << 20));                    // 16.5 MiB
    int*    idx   = (int*)  (ws + (34u << 20));
    float*  ew    = (float*)(ws + (34u << 20) + 1 * 65536);
    int*    stok  = (int*)  (ws + (34u << 20) + 2 * 65536);
    float*  sew   = (float*)(ws + (34u << 20) + 3 * 65536);
    int*    tslot = (int*)  (ws + (34u << 20) + 4 * 65536);
    int*    eoff  = (int*)  (ws + (34u << 20) + 5 * 65536);

    k_rmsnorm<<<1024, 256, 0, stream>>>(x, nsc, t32, t16);
    k_gate   <<<1024, 256, 0, stream>>>(t32, gw, gb, idx, ew);
    k_bucket <<<   1, 256, 0, stream>>>(idx, ew, eoff, stok, sew, tslot);
    k_gemm<0><<<dim3(16, 64), 256, 0, stream>>>(w1, b1, t16, eoff, stok, sew, act, nullptr);
    k_gemm<1><<<dim3( 8, 64), 256, 0, stream>>>(w2, b2, act, eoff, stok, sew, nullptr, obuf);
    k_combine<<<1024, 256, 0, stream>>>(x, obuf, tslot, out);
}

// Round 3
// 270.752 us; speedup vs baseline: 1.0885x; 1.0603x over previous
//
#include <hip/hip_runtime.h>
#include <hip/hip_bf16.h>

#define GLOBAL_AS __attribute__((address_space(1)))
#define LDS_AS    __attribute__((address_space(3)))

typedef __bf16 bf16x8 __attribute__((ext_vector_type(8)));
typedef __bf16 bf16x4 __attribute__((ext_vector_type(4)));
typedef float  f32x4v __attribute__((ext_vector_type(4)));

// ---------------- K1: RMSNorm -> t_f32, t_bf16 ----------------
__global__ __launch_bounds__(256) void k_rmsnorm(const float* __restrict__ x,
        const float* __restrict__ sc, float* __restrict__ t32,
        __bf16* __restrict__ t16)
{
    const int t = blockIdx.x, tid = threadIdx.x;
    const float4 v = ((const float4*)(x + (size_t)t * 1024))[tid];
    float ss = v.x*v.x + v.y*v.y + v.z*v.z + v.w*v.w;
    #pragma unroll
    for (int s = 32; s; s >>= 1) ss += __shfl_xor(ss, s, 64);
    __shared__ float red[4];
    if ((tid & 63) == 0) red[tid >> 6] = ss;
    __syncthreads();
    const float tot = red[0] + red[1] + red[2] + red[3];
    const float rs = rsqrtf(tot * (1.0f / 1024.0f) + 1e-5f);
    const float4 s4 = ((const float4*)sc)[tid];
    float4 o;
    o.x = v.x * rs * s4.x; o.y = v.y * rs * s4.y;
    o.z = v.z * rs * s4.z; o.w = v.w * rs * s4.w;
    ((float4*)(t32 + (size_t)t * 1024))[tid] = o;
    bf16x4 p;
    p[0] = (__bf16)o.x; p[1] = (__bf16)o.y; p[2] = (__bf16)o.z; p[3] = (__bf16)o.w;
    ((bf16x4*)(t16 + (size_t)t * 1024))[tid] = p;
}

// ---------------- K2: gate logits (fp32) + top4 + softmax ----------------
__global__ __launch_bounds__(256) void k_gate(const float* __restrict__ t32,
        const float* __restrict__ gw, const float* __restrict__ gb,
        int* __restrict__ idx, float* __restrict__ ew)
{
    const int t = blockIdx.x, tid = threadIdx.x;
    __shared__ float4 tl[256];
    __shared__ float part[4][64];
    tl[tid] = ((const float4*)(t32 + (size_t)t * 1024))[tid];
    __syncthreads();
    const int q = tid >> 6, e = tid & 63;
    const float4* w4 = (const float4*)(gw + (size_t)e * 1024 + q * 256);
    const float4* a4 = &tl[q * 64];
    float acc = 0.0f;
    #pragma unroll 8
    for (int i = 0; i < 64; ++i) {
        const float4 a = a4[i], b = w4[i];
        acc += a.x*b.x + a.y*b.y + a.z*b.z + a.w*b.w;
    }
    part[q][e] = acc;
    __syncthreads();
    if (tid < 64) {
        float cur = part[0][tid] + part[1][tid] + part[2][tid] + part[3][tid] + gb[tid];
        float vals[4]; int ids[4];
        #pragma unroll
        for (int k = 0; k < 4; ++k) {
            float m = cur;
            #pragma unroll
            for (int s = 32; s; s >>= 1) m = fmaxf(m, __shfl_xor(m, s, 64));
            const unsigned long long b = __ballot(cur == m);
            const int bi = __ffsll(b) - 1;
            vals[k] = m; ids[k] = bi;
            if (tid == bi) cur = -3.0e38f;
        }
        float ex[4], s = 0.0f;
        #pragma unroll
        for (int k = 0; k < 4; ++k) { ex[k] = expf(vals[k] - vals[0]); s += ex[k]; }
        if (tid < 4) { idx[t * 4 + tid] = ids[tid]; ew[t * 4 + tid] = ex[tid] / s; }
    }
}

// ---------------- K3: bucket (token,expert) pairs by expert ----------------
__global__ __launch_bounds__(256) void k_bucket(const int* __restrict__ idx,
        const float* __restrict__ ewv, int* __restrict__ eoff,
        int* __restrict__ slot_token, float* __restrict__ slot_ew,
        int* __restrict__ token_slots)
{
    __shared__ int cnt[64], cur[64];
    const int tid = threadIdx.x;
    if (tid < 64) cnt[tid] = 0;
    __syncthreads();
    for (int p = tid; p < 4096; p += 256) atomicAdd(&cnt[idx[p]], 1);
    __syncthreads();
    if (tid == 0) {
        int s = 0;
        for (int e = 0; e < 64; ++e) { eoff[e] = s; cur[e] = s; s += cnt[e]; }
        eoff[64] = s;
    }
    __syncthreads();
    for (int p = tid; p < 4096; p += 256) {
        const int e = idx[p];
        const int s = atomicAdd(&cur[e], 1);
        slot_token[s] = p >> 2;
        slot_ew[s] = ewv[p];
        token_slots[p] = s;
    }
}

// ---------------- K4/K5: grouped GEMM, 128x128 tile, BK=64, bf16 MFMA ----------------
// K-phase de-correlated per block (anti channel-camping on 4KB row stride),
// XCD-chunked (e,nt) mapping for A-side L2 locality, exact tail peel.
template<int MODE>
__global__ __launch_bounds__(256, 2) void k_gemm(
        const float* __restrict__ W, const float* __restrict__ Bias,
        const __bf16* __restrict__ A,
        const int* __restrict__ eoff, const int* __restrict__ slot_token,
        const float* __restrict__ slot_ew,
        __bf16* __restrict__ act_out, float* __restrict__ o_buf)
{
    constexpr int NPE = (MODE == 0) ? 2048 : 1024;
    const int d  = blockIdx.y * gridDim.x + blockIdx.x;   // linear dispatch id
    const int e  = (d & 7) * 8 + ((d >> 3) & 7);          // XCD-chunked expert map
    const int nt = d >> 6;
    const int ph = (d * 7) & 15;                          // K-phase
    const int off = eoff[e];
    const int count = eoff[e + 1] - off;
    if (count == 0) return;
    const int tid = threadIdx.x;
    const int wv = tid >> 6, l = tid & 63;
    const int wm = wv >> 1, wn = wv & 1;

    __shared__ __attribute__((aligned(16))) unsigned char lds[2][32768];

    const float* Wb = W + (size_t)e * NPE * 1024 + (size_t)nt * 128 * 1024;

#define KCOL(kt) ((ph + (kt)) & 15)

#define DMA_A(sbuf, kt) do {                                                   \
    const int kc_ = KCOL(kt);                                                  \
    _Pragma("unroll")                                                          \
    for (int i_ = 0; i_ < 4; ++i_)                                             \
        __builtin_amdgcn_global_load_lds(                                      \
            (const GLOBAL_AS void*)(asrc[i_] + kc_ * 128),                     \
            (LDS_AS void*)&lds[sbuf][(wv * 4 + i_) * 1024], 16, 0, 0);         \
    } while (0)

#define LOAD_B(dst, kt) do {                                                   \
    const int kc_ = KCOL(kt);                                                  \
    _Pragma("unroll")                                                          \
    for (int it_ = 0; it_ < 8; ++it_) {                                        \
        const int fid_ = it_ * 256 + tid;                                      \
        dst[it_] = *(const float4*)(Wb + (size_t)(fid_ >> 4) * 1024            \
                                    + kc_ * 64 + (fid_ & 15) * 4);             \
    } } while (0)

#define WRITE_B(src, sbuf) do {                                                \
    _Pragma("unroll")                                                          \
    for (int it_ = 0; it_ < 8; ++it_) {                                        \
        const int fid_ = it_ * 256 + tid;                                      \
        const int row_ = fid_ >> 4, c4_ = fid_ & 15;                           \
        bf16x4 p_;                                                             \
        p_[0] = (__bf16)src[it_].x; p_[1] = (__bf16)src[it_].y;                \
        p_[2] = (__bf16)src[it_].z; p_[3] = (__bf16)src[it_].w;                \
        *(bf16x4*)(&lds[sbuf][16384 + row_ * 128 +                             \
                   ((c4_ * 8) ^ ((row_ & 7) << 4))]) = p_;                     \
    } } while (0)

#define COMPUTE(cbuf) do {                                                     \
    _Pragma("unroll")                                                          \
    for (int kk_ = 0; kk_ < 2; ++kk_) {                                        \
        bf16x8 af_[4], bf_[4];                                                 \
        _Pragma("unroll")                                                      \
        for (int m_ = 0; m_ < 4; ++m_) {                                       \
            const int row_ = wm * 64 + m_ * 16 + (l & 15);                     \
            af_[m_] = *(const bf16x8*)(&lds[cbuf][row_ * 128 +                 \
                      ((kk_ * 64 + ((l >> 4) * 16)) ^ ((row_ & 7) << 4))]);    \
        }                                                                      \
        _Pragma("unroll")                                                      \
        for (int n_ = 0; n_ < 4; ++n_) {                                       \
            const int row_ = wn * 64 + n_ * 16 + (l & 15);                     \
            bf_[n_] = *(const bf16x8*)(&lds[cbuf][16384 + row_ * 128 +         \
                      ((kk_ * 64 + ((l >> 4) * 16)) ^ ((row_ & 7) << 4))]);    \
        }                                                                      \
        _Pragma("unroll")                                                      \
        for (int m_ = 0; m_ < 4; ++m_)                                         \
            _Pragma("unroll")                                                  \
            for (int n_ = 0; n_ < 4; ++n_)                                     \
                acc[m_][n_] = __builtin_amdgcn_mfma_f32_16x16x32_bf16(         \
                                  af_[m_], bf_[n_], acc[m_][n_], 0, 0, 0);     \
    } } while (0)

    for (int mt = 0; mt * 128 < count; ++mt) {
        const unsigned char* asrc[4];
        #pragma unroll
        for (int i = 0; i < 4; ++i) {
            const int chunk = wv * 4 + i;
            const int row = chunk * 8 + (l >> 3);
            const int colbyte = ((l & 7) ^ (l >> 3)) << 4;
            int arow;
            if (MODE == 0) {
                int slot = off + mt * 128 + row;
                const int smax = off + count - 1;
                if (slot > smax) slot = smax;
                arow = slot_token[slot];
            } else {
                arow = off + mt * 128 + row;
            }
            asrc[i] = (const unsigned char*)A + (size_t)arow * 2048 + colbyte;
        }

        f32x4v acc[4][4];
        #pragma unroll
        for (int m = 0; m < 4; ++m)
            #pragma unroll
            for (int n = 0; n < 4; ++n)
                acc[m][n] = f32x4v{0.f, 0.f, 0.f, 0.f};

        float4 bvA[8], bvB[8];

        // ---- prologue: lds[0] <- {A(0), B(0)}, bvA <- B(1) in flight ----
        DMA_A(0, 0);
        __builtin_amdgcn_sched_barrier(0);
        LOAD_B(bvA, 0);
        WRITE_B(bvA, 0);                 // reg dep drains B(0) (and older A-dma)
        __builtin_amdgcn_sched_barrier(0);
        LOAD_B(bvA, 1);
        asm volatile("s_waitcnt lgkmcnt(0)" ::: "memory");
        __builtin_amdgcn_sched_barrier(0);
        __builtin_amdgcn_s_barrier();

        #pragma unroll 1
        for (int p = 0; p < 7; ++p) {
            const int kt0 = 2 * p, kt1 = 2 * p + 1;
            // even step: compute lds[0], stage lds[1]; bvA holds B(kt0+1)
            DMA_A(1, kt0 + 1);
            __builtin_amdgcn_sched_barrier(0);
            LOAD_B(bvB, kt0 + 2);
            __builtin_amdgcn_sched_barrier(0);
            COMPUTE(0);
            WRITE_B(bvA, 1);
            asm volatile("s_waitcnt vmcnt(8) lgkmcnt(0)" ::: "memory");
            __builtin_amdgcn_sched_barrier(0);
            __builtin_amdgcn_s_barrier();
            // odd step: compute lds[1], stage lds[0]; bvB holds B(kt1+1)
            DMA_A(0, kt1 + 1);
            __builtin_amdgcn_sched_barrier(0);
            LOAD_B(bvA, kt1 + 2);
            __builtin_amdgcn_sched_barrier(0);
            COMPUTE(1);
            WRITE_B(bvB, 0);
            asm volatile("s_waitcnt vmcnt(8) lgkmcnt(0)" ::: "memory");
            __builtin_amdgcn_sched_barrier(0);
            __builtin_amdgcn_s_barrier();
        }

        // ---- tail: steps 14, 15 (no over-prefetch) ----
        // entering: lds[0] = {A(14),B(14)}, bvA = B(15)
        DMA_A(1, 15);
        __builtin_amdgcn_sched_barrier(0);
        COMPUTE(0);                      // tile 14
        WRITE_B(bvA, 1);                 // B(15)
        asm volatile("s_waitcnt vmcnt(0) lgkmcnt(0)" ::: "memory");
        __builtin_amdgcn_sched_barrier(0);
        __builtin_amdgcn_s_barrier();
        COMPUTE(1);                      // tile 15

        // ---- epilogue ----
        #pragma unroll
        for (int m = 0; m < 4; ++m) {
            #pragma unroll
            for (int n = 0; n < 4; ++n) {
                #pragma unroll
                for (int j = 0; j < 4; ++j) {
                    const int row  = wm * 64 + m * 16 + (l >> 4) * 4 + j;
                    const int coll = wn * 64 + n * 16 + (l & 15);
                    const int gn = nt * 128 + coll;
                    const int gm = mt * 128 + row;
                    if (MODE == 0) {
                        float v = acc[m][n][j] + Bias[(size_t)e * NPE + gn];
                        const float partner = __shfl_xor(v, 1, 64);
                        if (!(l & 1) && gm < count) {
                            const float g  = fminf(v, 7.0f);
                            const float lv = fminf(fmaxf(partner, -7.0f), 7.0f);
                            const float r  = g / (1.0f + expf(-1.702f * g)) * (lv + 1.0f);
                            act_out[(size_t)(off + gm) * 1024 + (gn >> 1)] = (__bf16)r;
                        }
                    } else {
                        if (gm < count) {
                            const int slot = off + gm;
                            const float v = acc[m][n][j] + Bias[(size_t)e * NPE + gn];
                            o_buf[(size_t)slot * 1024 + gn] = v * slot_ew[slot];
                        }
                    }
                }
            }
        }
    }
#undef DMA_A
#undef LOAD_B
#undef WRITE_B
#undef COMPUTE
#undef KCOL
}

// ---------------- K6: out = x + sum_k o_buf[slot(t,k)] ----------------
__global__ __launch_bounds__(256) void k_combine(const float* __restrict__ x,
        const float* __restrict__ o_buf, const int* __restrict__ tslot,
        float* __restrict__ out)
{
    const int t = blockIdx.x, tid = threadIdx.x;
    float4 r = ((const float4*)(x + (size_t)t * 1024))[tid];
    #pragma unroll
    for (int k = 0; k < 4; ++k) {
        const int s = tslot[t * 4 + k];
        const float4 o = ((const float4*)(o_buf + (size_t)s * 1024))[tid];
        r.x += o.x; r.y += o.y; r.z += o.z; r.w += o.w;
    }
    ((float4*)(out + (size_t)t * 1024))[tid] = r;
}

extern "C" void kernel_launch(void* const* d_in, const int* in_sizes, int n_in,
                              void* d_out, int out_size, void* d_ws, size_t ws_size,
                              hipStream_t stream)
{
    const float* x   = (const float*)d_in[0];
    const float* nsc = (const float*)d_in[1];
    const float* gw  = (const float*)d_in[2];
    const float* gb  = (const float*)d_in[3];
    const float* w1  = (const float*)d_in[4];
    const float* b1  = (const float*)d_in[5];
    const float* w2  = (const float*)d_in[6];
    const float* b2  = (const float*)d_in[7];
    float* out = (float*)d_out;
    (void)in_sizes; (void)n_in; (void)out_size; (void)ws_size;

    char* ws = (char*)d_ws;
    float*  t32   = (float*)(ws);                                  // 4 MiB
    __bf16* t16   = (__bf16*)(ws + (4u  << 20));                   // 2 MiB
    __bf16* act   = (__bf16*)(ws + (6u  << 20));                   // 4224*1024*2 B
    float*  obuf  = (float*)(ws + (16u << 20));                    // 16.5 MiB
    int*    idx   = (int*)  (ws + (34u << 20));
    float*  ew    = (float*)(ws + (34u << 20) + 1 * 65536);
    int*    stok  = (int*)  (ws + (34u << 20) + 2 * 65536);
    float*  sew   = (float*)(ws + (34u << 20) + 3 * 65536);
    int*    tslot = (int*)  (ws + (34u << 20) + 4 * 65536);
    int*    eoff  = (int*)  (ws + (34u << 20) + 5 * 65536);

    k_rmsnorm<<<1024, 256, 0, stream>>>(x, nsc, t32, t16);
    k_gate   <<<1024, 256, 0, stream>>>(t32, gw, gb, idx, ew);
    k_bucket <<<   1, 256, 0, stream>>>(idx, ew, eoff, stok, sew, tslot);
    k_gemm<0><<<dim3(16, 64), 256, 0, stream>>>(w1, b1, t16, eoff, stok, sew, act, nullptr);
    k_gemm<1><<<dim3( 8, 64), 256, 0, stream>>>(w2, b2, act, eoff, stok, sew, nullptr, obuf);
    k_combine<<<1024, 256, 0, stream>>>(x, obuf, tslot, out);
}